// Round 2
// baseline (438.055 us; speedup 1.0000x reference)
//
#include <hip/hip_runtime.h>
#include <hip/hip_bf16.h>
#include <math.h>

// Problem: B=4, T=2048, C=1024, H=16, D=64, d_half=32
// Dataflow:
//   cast x, w_attn, w_proj -> bf16
//   qkvb = xb @ wab^T  rope+rmsnorm fused into q/k epilogue; v written
//          PRE-TRANSPOSED to vt[b*C + h*64 + d][t] (packed short4 over r)
//   attn (bf16 MFMA flash, fixed-max softmax, fold-paired q-tiles):
//          K and V^T fragments loaded DIRECTLY global->reg (L1/L2-resident
//          tiles; 4 quad-lanes share each 64B line, fully coalesced lines).
//          No LDS staging, no __syncthreads in the kt loop. Ps (P round-trip
//          for the PV transpose) is the only LDS use, XOR-swizzled.
//          y written into qkvb's dead v-columns.
//   out  = (qkvb v-cols as y, lda=3072) @ wpb^T  (fp32 out)

#define TT 2048
#define CC 1024
#define HH 16
#define DD 64

typedef __attribute__((ext_vector_type(8))) short short8;
typedef __attribute__((ext_vector_type(4))) short short4_t;
typedef __attribute__((ext_vector_type(4))) float f32x4;
typedef unsigned short ushort_t;

// fp32 -> bf16 (RNE, finite inputs only)
__device__ __forceinline__ ushort_t f2bf(float f) {
    unsigned u = __builtin_bit_cast(unsigned, f);
    u = (u + 0x7fffu + ((u >> 16) & 1u)) >> 16;
    return (ushort_t)u;
}

// ---------------------------------------------------------------------------
// float -> bf16 cast, 8 elements/thread
// ---------------------------------------------------------------------------
__global__ __launch_bounds__(256) void cast_bf16(const float* __restrict__ in,
                                                 ushort_t* __restrict__ out, int n8) {
    const int i = blockIdx.x * 256 + threadIdx.x;
    if (i >= n8) return;
    const float4* p = (const float4*)in + (size_t)i * 2;
    float4 f0 = p[0], f1 = p[1];
    short8 v;
    v[0] = (short)f2bf(f0.x); v[1] = (short)f2bf(f0.y);
    v[2] = (short)f2bf(f0.z); v[3] = (short)f2bf(f0.w);
    v[4] = (short)f2bf(f1.x); v[5] = (short)f2bf(f1.y);
    v[6] = (short)f2bf(f1.z); v[7] = (short)f2bf(f1.w);
    *(short8*)(out + (size_t)i * 8) = v;
}

// ---------------------------------------------------------------------------
// bf16 MFMA GEMM (m97 structure): C = A[M,K](lda) * B[N,K]^T, 128x128 tile.
// ---------------------------------------------------------------------------
template <bool OUTF32>
__global__ __launch_bounds__(256) void gemm_bt(const ushort_t* __restrict__ A,
                                               const ushort_t* __restrict__ B,
                                               void* __restrict__ C,
                                               int M, int N, int K, int lda) {
    __shared__ ushort_t As[128 * 32];
    __shared__ ushort_t Bs[128 * 32];

    const int tid  = threadIdx.x;
    const int wv   = tid >> 6;
    const int ln   = tid & 63;
    const int quad = ln >> 4;
    const int lm   = ln & 15;
    const int wm   = wv & 1;
    const int wn   = wv >> 1;
    const int rowC = blockIdx.y * 128;
    const int colC = blockIdx.x * 128;

    const int srow = wv * 16 + (ln >> 2);
    const int skq  = (ln & 3) * 8;

    f32x4 acc[4][4];
#pragma unroll
    for (int i = 0; i < 4; ++i)
#pragma unroll
        for (int j = 0; j < 4; ++j) acc[i][j] = (f32x4){0.f, 0.f, 0.f, 0.f};

    for (int k0 = 0; k0 < K; k0 += 32) {
        __syncthreads();
#pragma unroll
        for (int half = 0; half < 2; ++half) {
            const ushort_t* gA = A + (size_t)(rowC + half * 64 + srow) * lda + k0 + skq;
            const ushort_t* gB = B + (size_t)(colC + half * 64 + srow) * K + k0 + skq;
            ushort_t* lA = As + (half * 64 + wv * 16) * 32;
            ushort_t* lB = Bs + (half * 64 + wv * 16) * 32;
            __builtin_amdgcn_global_load_lds(
                (const __attribute__((address_space(1))) unsigned int*)gA,
                (__attribute__((address_space(3))) unsigned int*)lA, 16, 0, 0);
            __builtin_amdgcn_global_load_lds(
                (const __attribute__((address_space(1))) unsigned int*)gB,
                (__attribute__((address_space(3))) unsigned int*)lB, 16, 0, 0);
        }
        __syncthreads();

        short8 af[4], bf[4];
#pragma unroll
        for (int mt = 0; mt < 4; ++mt)
            af[mt] = *(const short8*)&As[(wm * 64 + mt * 16 + lm) * 32 + quad * 8];
#pragma unroll
        for (int nt = 0; nt < 4; ++nt)
            bf[nt] = *(const short8*)&Bs[(wn * 64 + nt * 16 + lm) * 32 + quad * 8];
#pragma unroll
        for (int mt = 0; mt < 4; ++mt)
#pragma unroll
            for (int nt = 0; nt < 4; ++nt)
                acc[mt][nt] = __builtin_amdgcn_mfma_f32_16x16x32_bf16(
                    af[mt], bf[nt], acc[mt][nt], 0, 0, 0);
    }

#pragma unroll
    for (int mt = 0; mt < 4; ++mt)
#pragma unroll
        for (int r = 0; r < 4; ++r) {
            const size_t row = rowC + wm * 64 + mt * 16 + quad * 4 + r;
#pragma unroll
            for (int nt = 0; nt < 4; ++nt) {
                const size_t col = colC + wn * 64 + nt * 16 + lm;
                if (OUTF32) ((float*)C)[row * N + col] = acc[mt][nt][r];
                else        ((ushort_t*)C)[row * N + col] = f2bf(acc[mt][nt][r]);
            }
        }
}

// ---------------------------------------------------------------------------
// GEMM1 with fused rope+rmsnorm epilogue on q/k. v-section written
// TRANSPOSED to vtb[(b*CC + h*64 + d)][t] as packed short4 (r = 4 consec t).
// ---------------------------------------------------------------------------
__global__ __launch_bounds__(256) void gemm_qkv(const ushort_t* __restrict__ A,
                                                const ushort_t* __restrict__ B,
                                                ushort_t* __restrict__ C,
                                                ushort_t* __restrict__ vtb,
                                                const float* __restrict__ cosb,
                                                const float* __restrict__ sinb,
                                                int M, int N, int K) {
    __shared__ ushort_t As[128 * 32];
    __shared__ ushort_t Bs[128 * 32];

    const int tid  = threadIdx.x;
    const int wv   = tid >> 6;
    const int ln   = tid & 63;
    const int quad = ln >> 4;
    const int lm   = ln & 15;
    const int wm   = wv & 1;
    const int wn   = wv >> 1;
    const int rowC = blockIdx.y * 128;
    const int colC = blockIdx.x * 128;

    const int srow = wv * 16 + (ln >> 2);
    const int skq  = (ln & 3) * 8;

    f32x4 acc[4][4];
#pragma unroll
    for (int i = 0; i < 4; ++i)
#pragma unroll
        for (int j = 0; j < 4; ++j) acc[i][j] = (f32x4){0.f, 0.f, 0.f, 0.f};

    for (int k0 = 0; k0 < K; k0 += 32) {
        __syncthreads();
#pragma unroll
        for (int half = 0; half < 2; ++half) {
            const ushort_t* gA = A + (size_t)(rowC + half * 64 + srow) * K + k0 + skq;
            const ushort_t* gB = B + (size_t)(colC + half * 64 + srow) * K + k0 + skq;
            ushort_t* lA = As + (half * 64 + wv * 16) * 32;
            ushort_t* lB = Bs + (half * 64 + wv * 16) * 32;
            __builtin_amdgcn_global_load_lds(
                (const __attribute__((address_space(1))) unsigned int*)gA,
                (__attribute__((address_space(3))) unsigned int*)lA, 16, 0, 0);
            __builtin_amdgcn_global_load_lds(
                (const __attribute__((address_space(1))) unsigned int*)gB,
                (__attribute__((address_space(3))) unsigned int*)lB, 16, 0, 0);
        }
        __syncthreads();

        short8 af[4], bf[4];
#pragma unroll
        for (int mt = 0; mt < 4; ++mt)
            af[mt] = *(const short8*)&As[(wm * 64 + mt * 16 + lm) * 32 + quad * 8];
#pragma unroll
        for (int nt = 0; nt < 4; ++nt)
            bf[nt] = *(const short8*)&Bs[(wn * 64 + nt * 16 + lm) * 32 + quad * 8];
#pragma unroll
        for (int mt = 0; mt < 4; ++mt)
#pragma unroll
            for (int nt = 0; nt < 4; ++nt)
                acc[mt][nt] = __builtin_amdgcn_mfma_f32_16x16x32_bf16(
                    af[mt], bf[nt], acc[mt][nt], 0, 0, 0);
    }

    const bool isqk = colC < 2 * CC;   // q or k section
    if (isqk) {
#pragma unroll
        for (int mt = 0; mt < 4; ++mt)
#pragma unroll
            for (int r = 0; r < 4; ++r) {
                const int row = rowC + wm * 64 + mt * 16 + quad * 4 + r;
                ushort_t* Cp = C + (size_t)row * N + colC + wn * 64 + lm;
                const int t = row & (TT - 1);
                float ss = 0.f;
#pragma unroll
                for (int nt = 0; nt < 4; ++nt) ss += acc[mt][nt][r] * acc[mt][nt][r];
                ss += __shfl_xor(ss, 1);
                ss += __shfl_xor(ss, 2);
                ss += __shfl_xor(ss, 4);
                ss += __shfl_xor(ss, 8);
                const float rinv = rsqrtf(ss * (1.0f / 64.0f) + 1e-6f);
                const float c0 = cosb[t * 32 + lm];
                const float c1 = cosb[t * 32 + 16 + lm];
                const float s0 = sinb[t * 32 + lm];
                const float s1 = sinb[t * 32 + 16 + lm];
                const float o0 = acc[mt][0][r] * c0 + acc[mt][2][r] * s0;
                const float o1 = acc[mt][1][r] * c1 + acc[mt][3][r] * s1;
                const float o2 = acc[mt][2][r] * c0 - acc[mt][0][r] * s0;
                const float o3 = acc[mt][3][r] * c1 - acc[mt][1][r] * s1;
                Cp[0]  = f2bf(o0 * rinv);
                Cp[16] = f2bf(o1 * rinv);
                Cp[32] = f2bf(o2 * rinv);
                Cp[48] = f2bf(o3 * rinv);
            }
    } else {
        // v: write transposed. Lane's 4 r-values are 4 consecutive t at one
        // (h,d) row -> one packed 8B store each nt.
#pragma unroll
        for (int mt = 0; mt < 4; ++mt) {
            const int row0 = rowC + wm * 64 + mt * 16 + quad * 4;
            const int bb = row0 >> 11;         // batch
            const int tt = row0 & (TT - 1);    // t of r=0
#pragma unroll
            for (int nt = 0; nt < 4; ++nt) {
                const int hd = colC - 2 * CC + wn * 64 + nt * 16 + lm;
                short4_t pk;
                pk[0] = (short)f2bf(acc[mt][nt][0]);
                pk[1] = (short)f2bf(acc[mt][nt][1]);
                pk[2] = (short)f2bf(acc[mt][nt][2]);
                pk[3] = (short)f2bf(acc[mt][nt][3]);
                *(short4_t*)(vtb + (size_t)(bb * CC + hd) * TT + tt) = pk;
            }
        }
    }
}

// ---------------------------------------------------------------------------
// bf16 MFMA flash attention, fixed-max softmax, fold-paired q-tiles.
// K / V^T fragments loaded directly global->reg each kt (tiles are L1/L2
// resident; 4 quad-lanes share each 64B line). No LDS staging, no barriers.
// Ps (P transpose round-trip) is the only LDS use, XOR-swizzled
// (n' = (n>>3 ^ m>>2)<<3 | n&7). y written into qkv's dead v-columns.
// ---------------------------------------------------------------------------
__global__ __launch_bounds__(256, 3) void attn_mfma(ushort_t* __restrict__ qkv,
                                                    const ushort_t* __restrict__ vt) {
    const int qp = blockIdx.x;   // 0..15
    const int h  = blockIdx.y;   // 0..15
    const int b  = blockIdx.z;   // 0..3
    const int tid  = threadIdx.x;
    const int w    = tid >> 6;
    const int lane = tid & 63;
    const int quad = lane >> 4;
    const int lm   = lane & 15;
    const int qtA = qp, qtB = 31 - qp;

    __shared__ ushort_t Ps[4][16][72]; // per-wave P[m][n'], n' block-swizzled

    short8 qfA[2], qfB[2];
    {
        const ushort_t* qa = qkv + (size_t)(b * TT + qtA * 64 + w * 16 + lm) * (3 * CC) + h * DD;
        const ushort_t* qb = qkv + (size_t)(b * TT + qtB * 64 + w * 16 + lm) * (3 * CC) + h * DD;
        qfA[0] = *(const short8*)(qa + quad * 8);
        qfA[1] = *(const short8*)(qa + 32 + quad * 8);
        qfB[0] = *(const short8*)(qb + quad * 8);
        qfB[1] = *(const short8*)(qb + 32 + quad * 8);
    }

    f32x4 OA[4], OB[4];
#pragma unroll
    for (int dt = 0; dt < 4; ++dt) {
        OA[dt] = (f32x4){0.f, 0.f, 0.f, 0.f};
        OB[dt] = (f32x4){0.f, 0.f, 0.f, 0.f};
    }
    float psA[4] = {0.f, 0.f, 0.f, 0.f};
    float psB[4] = {0.f, 0.f, 0.f, 0.f};

    // per-lane base pointers for direct K / V^T fragment loads
    // kf[kk][i] = K[t = kt*64 + i*16+lm][d = kk*32 + quad*8 ..]
    // vf[kk][i] = V^T[d = i*16+lm][n = kt*64 + kk*32 + quad*8 ..]
    const ushort_t* kbase = qkv + (size_t)(b * TT + lm) * (3 * CC) + CC + h * DD + quad * 8;
    const ushort_t* vbase = vt + (size_t)(b * CC + h * DD + lm) * TT + quad * 8;

    auto process = [&](const short8 (&qf)[2], const short8 (&kf)[2][4],
                       const short8 (&vf)[2][4], f32x4 (&O)[4], float (&ps)[4],
                       bool diag) {
        f32x4 sf[4];
#pragma unroll
        for (int nt = 0; nt < 4; ++nt) sf[nt] = (f32x4){0.f, 0.f, 0.f, 0.f};
#pragma unroll
        for (int kk = 0; kk < 2; ++kk)
#pragma unroll
            for (int nt = 0; nt < 4; ++nt)
                sf[nt] = __builtin_amdgcn_mfma_f32_16x16x32_bf16(qf[kk], kf[kk][nt],
                                                                 sf[nt], 0, 0, 0);
        // p = exp(s*0.125 - 8); scores provably in [-8,8] after rmsnorm.
#pragma unroll
        for (int r = 0; r < 4; ++r) {
            const int rloc = w * 16 + quad * 4 + r;   // row within q-tile
            const int m = quad * 4 + r;
#pragma unroll
            for (int nt = 0; nt < 4; ++nt) {
                const int n = nt * 16 + lm;
                float s = sf[nt][r] * 0.125f - 8.f;
                if (diag) s = (n <= rloc) ? s : -1e30f;
                const float p = __expf(s);
                ps[r] += p;
                Ps[w][m][(((n >> 3) ^ (m >> 2)) << 3) | (n & 7)] = f2bf(p);
            }
        }
#pragma unroll
        for (int kk = 0; kk < 2; ++kk) {
            const short8 pf =
                *(const short8*)&Ps[w][lm][(((kk * 4 + quad) ^ (lm >> 2)) << 3)];
#pragma unroll
            for (int dt = 0; dt < 4; ++dt)
                O[dt] = __builtin_amdgcn_mfma_f32_16x16x32_bf16(pf, vf[kk][dt],
                                                                O[dt], 0, 0, 0);
        }
    };

    for (int kt = 0; kt <= qtB; ++kt) {
        const ushort_t* kp = kbase + (size_t)kt * 64 * (3 * CC);
        const ushort_t* vp = vbase + kt * 64;
        short8 kf[2][4], vf[2][4];
#pragma unroll
        for (int i = 0; i < 4; ++i) {
            const ushort_t* kpi = kp + (size_t)i * 16 * (3 * CC);
            const ushort_t* vpi = vp + (size_t)i * 16 * TT;
            kf[0][i] = *(const short8*)kpi;
            kf[1][i] = *(const short8*)(kpi + 32);
            vf[0][i] = *(const short8*)vpi;
            vf[1][i] = *(const short8*)(vpi + 32);
        }

        if (kt <= qtA) process(qfA, kf, vf, OA, psA, kt == qtA);
        process(qfB, kf, vf, OB, psB, kt == qtB);
    }

    // epilogue: reduce row sums once, scale, store into qkv's v-columns
    auto epi = [&](f32x4 (&O)[4], float (&ps)[4], int qt) {
#pragma unroll
        for (int r = 0; r < 4; ++r) {
            float l = ps[r];
            l += __shfl_xor(l, 1);
            l += __shfl_xor(l, 2);
            l += __shfl_xor(l, 4);
            l += __shfl_xor(l, 8);
            const float inv_l = 1.f / l;
            ushort_t* yp = qkv + (size_t)(b * TT + qt * 64 + w * 16 + quad * 4 + r) * (3 * CC)
                               + 2 * CC + h * DD + lm;
#pragma unroll
            for (int dt = 0; dt < 4; ++dt) yp[dt * 16] = f2bf(O[dt][r] * inv_l);
        }
    };
    epi(OA, psA, qtA);
    epi(OB, psB, qtB);
}

// ---------------------------------------------------------------------------
extern "C" void kernel_launch(void* const* d_in, const int* in_sizes, int n_in,
                              void* d_out, int out_size, void* d_ws, size_t ws_size,
                              hipStream_t stream) {
    const float* x      = (const float*)d_in[0];   // (4,2048,1024)
    const float* cosb   = (const float*)d_in[1];   // (1,2048,1,32)
    const float* sinb   = (const float*)d_in[2];
    const float* w_attn = (const float*)d_in[3];   // (3072,1024)
    const float* w_proj = (const float*)d_in[4];   // (1024,1024)
    float* out = (float*)d_out;                    // (4,2048,1024)

    // workspace layout (bf16 elements)
    ushort_t* qkvb = (ushort_t*)d_ws;                       // 8192*3072 (q,k; v-cols hold y)
    ushort_t* vtb  = qkvb + (size_t)8192 * 3072;            // 4096*2048 = 8192*1024 (V^T)
    ushort_t* xb   = vtb  + (size_t)8192 * 1024;            // 8192*1024
    ushort_t* wab  = xb   + (size_t)8192 * 1024;            // 3072*1024
    ushort_t* wpb  = wab  + (size_t)3072 * 1024;            // 1024*1024

    cast_bf16<<<(8192 * 1024 / 8 + 255) / 256, 256, 0, stream>>>(x, xb, 8192 * 1024 / 8);
    cast_bf16<<<(3072 * 1024 / 8 + 255) / 256, 256, 0, stream>>>(w_attn, wab, 3072 * 1024 / 8);
    cast_bf16<<<(1024 * 1024 / 8 + 255) / 256, 256, 0, stream>>>(w_proj, wpb, 1024 * 1024 / 8);

    // qkv = x @ w_attn^T; rope+rmsnorm on q,k; v transposed into vtb
    gemm_qkv<<<dim3(3072 / 128, 8192 / 128), 256, 0, stream>>>(
        xb, wab, qkvb, vtb, cosb, sinb, 8192, 3072, 1024);

    // causal attention -> y into qkvb's v-columns
    attn_mfma<<<dim3(16, HH, 4), 256, 0, stream>>>(qkvb, vtb);

    // out = y @ w_proj^T (fp32 out), A = qkvb v-columns with lda=3072
    gemm_bt<true><<<dim3(1024 / 128, 8192 / 128), 256, 0, stream>>>(
        qkvb + 2 * CC, wpb, out, 8192, 1024, 1024, 3 * CC);
}

// Round 3
// 312.303 us; speedup vs baseline: 1.4027x; 1.4027x over previous
//
#include <hip/hip_runtime.h>
#include <hip/hip_bf16.h>
#include <math.h>

// Problem: B=4, T=2048, C=1024, H=16, D=64, d_half=32
// Dataflow:
//   cast x, w_attn, w_proj -> bf16
//   qkvb = xb @ wab^T  rope+rmsnorm fused into q/k epilogue; v written
//          PRE-TRANSPOSED to vt[b*C + h*64 + d][t] (packed short4 over r)
//   attn (bf16 MFMA flash, fixed-max softmax):
//          one q-tile per block (longest blocks dispatched first -> LPT
//          packing); double-buffered LDS K/V staging with early global
//          issue (2-phase pipeline); SWAPPED QK^T (mfma(K,Q)) with
//          k-relabeling so P stays entirely in registers (cvt_pk_bf16
//          pairs ARE the PV A-fragment); row sums via ones-column MFMA.
//          y written into qkvb's dead v-columns.
//   out  = (qkvb v-cols as y, lda=3072) @ wpb^T  (fp32 out)

#define TT 2048
#define CC 1024
#define HH 16
#define DD 64

typedef __attribute__((ext_vector_type(8))) short short8;
typedef __attribute__((ext_vector_type(4))) short short4_t;
typedef __attribute__((ext_vector_type(4))) float f32x4;
typedef __attribute__((ext_vector_type(4))) int int4v;
typedef unsigned short ushort_t;

// fp32 -> bf16 (RNE, finite inputs only)
__device__ __forceinline__ ushort_t f2bf(float f) {
    unsigned u = __builtin_bit_cast(unsigned, f);
    u = (u + 0x7fffu + ((u >> 16) & 1u)) >> 16;
    return (ushort_t)u;
}

// ---------------------------------------------------------------------------
// float -> bf16 cast, 8 elements/thread
// ---------------------------------------------------------------------------
__global__ __launch_bounds__(256) void cast_bf16(const float* __restrict__ in,
                                                 ushort_t* __restrict__ out, int n8) {
    const int i = blockIdx.x * 256 + threadIdx.x;
    if (i >= n8) return;
    const float4* p = (const float4*)in + (size_t)i * 2;
    float4 f0 = p[0], f1 = p[1];
    short8 v;
    v[0] = (short)f2bf(f0.x); v[1] = (short)f2bf(f0.y);
    v[2] = (short)f2bf(f0.z); v[3] = (short)f2bf(f0.w);
    v[4] = (short)f2bf(f1.x); v[5] = (short)f2bf(f1.y);
    v[6] = (short)f2bf(f1.z); v[7] = (short)f2bf(f1.w);
    *(short8*)(out + (size_t)i * 8) = v;
}

// ---------------------------------------------------------------------------
// bf16 MFMA GEMM (m97 structure): C = A[M,K](lda) * B[N,K]^T, 128x128 tile.
// ---------------------------------------------------------------------------
template <bool OUTF32>
__global__ __launch_bounds__(256) void gemm_bt(const ushort_t* __restrict__ A,
                                               const ushort_t* __restrict__ B,
                                               void* __restrict__ C,
                                               int M, int N, int K, int lda) {
    __shared__ ushort_t As[128 * 32];
    __shared__ ushort_t Bs[128 * 32];

    const int tid  = threadIdx.x;
    const int wv   = tid >> 6;
    const int ln   = tid & 63;
    const int quad = ln >> 4;
    const int lm   = ln & 15;
    const int wm   = wv & 1;
    const int wn   = wv >> 1;
    const int rowC = blockIdx.y * 128;
    const int colC = blockIdx.x * 128;

    const int srow = wv * 16 + (ln >> 2);
    const int skq  = (ln & 3) * 8;

    f32x4 acc[4][4];
#pragma unroll
    for (int i = 0; i < 4; ++i)
#pragma unroll
        for (int j = 0; j < 4; ++j) acc[i][j] = (f32x4){0.f, 0.f, 0.f, 0.f};

    for (int k0 = 0; k0 < K; k0 += 32) {
        __syncthreads();
#pragma unroll
        for (int half = 0; half < 2; ++half) {
            const ushort_t* gA = A + (size_t)(rowC + half * 64 + srow) * lda + k0 + skq;
            const ushort_t* gB = B + (size_t)(colC + half * 64 + srow) * K + k0 + skq;
            ushort_t* lA = As + (half * 64 + wv * 16) * 32;
            ushort_t* lB = Bs + (half * 64 + wv * 16) * 32;
            __builtin_amdgcn_global_load_lds(
                (const __attribute__((address_space(1))) unsigned int*)gA,
                (__attribute__((address_space(3))) unsigned int*)lA, 16, 0, 0);
            __builtin_amdgcn_global_load_lds(
                (const __attribute__((address_space(1))) unsigned int*)gB,
                (__attribute__((address_space(3))) unsigned int*)lB, 16, 0, 0);
        }
        __syncthreads();

        short8 af[4], bf[4];
#pragma unroll
        for (int mt = 0; mt < 4; ++mt)
            af[mt] = *(const short8*)&As[(wm * 64 + mt * 16 + lm) * 32 + quad * 8];
#pragma unroll
        for (int nt = 0; nt < 4; ++nt)
            bf[nt] = *(const short8*)&Bs[(wn * 64 + nt * 16 + lm) * 32 + quad * 8];
#pragma unroll
        for (int mt = 0; mt < 4; ++mt)
#pragma unroll
            for (int nt = 0; nt < 4; ++nt)
                acc[mt][nt] = __builtin_amdgcn_mfma_f32_16x16x32_bf16(
                    af[mt], bf[nt], acc[mt][nt], 0, 0, 0);
    }

#pragma unroll
    for (int mt = 0; mt < 4; ++mt)
#pragma unroll
        for (int r = 0; r < 4; ++r) {
            const size_t row = rowC + wm * 64 + mt * 16 + quad * 4 + r;
#pragma unroll
            for (int nt = 0; nt < 4; ++nt) {
                const size_t col = colC + wn * 64 + nt * 16 + lm;
                if (OUTF32) ((float*)C)[row * N + col] = acc[mt][nt][r];
                else        ((ushort_t*)C)[row * N + col] = f2bf(acc[mt][nt][r]);
            }
        }
}

// ---------------------------------------------------------------------------
// GEMM1 with fused rope+rmsnorm epilogue on q/k. v-section written
// TRANSPOSED to vtb[(b*CC + h*64 + d)][t] as packed short4 (r = 4 consec t).
// ---------------------------------------------------------------------------
__global__ __launch_bounds__(256) void gemm_qkv(const ushort_t* __restrict__ A,
                                                const ushort_t* __restrict__ B,
                                                ushort_t* __restrict__ C,
                                                ushort_t* __restrict__ vtb,
                                                const float* __restrict__ cosb,
                                                const float* __restrict__ sinb,
                                                int M, int N, int K) {
    __shared__ ushort_t As[128 * 32];
    __shared__ ushort_t Bs[128 * 32];

    const int tid  = threadIdx.x;
    const int wv   = tid >> 6;
    const int ln   = tid & 63;
    const int quad = ln >> 4;
    const int lm   = ln & 15;
    const int wm   = wv & 1;
    const int wn   = wv >> 1;
    const int rowC = blockIdx.y * 128;
    const int colC = blockIdx.x * 128;

    const int srow = wv * 16 + (ln >> 2);
    const int skq  = (ln & 3) * 8;

    f32x4 acc[4][4];
#pragma unroll
    for (int i = 0; i < 4; ++i)
#pragma unroll
        for (int j = 0; j < 4; ++j) acc[i][j] = (f32x4){0.f, 0.f, 0.f, 0.f};

    for (int k0 = 0; k0 < K; k0 += 32) {
        __syncthreads();
#pragma unroll
        for (int half = 0; half < 2; ++half) {
            const ushort_t* gA = A + (size_t)(rowC + half * 64 + srow) * K + k0 + skq;
            const ushort_t* gB = B + (size_t)(colC + half * 64 + srow) * K + k0 + skq;
            ushort_t* lA = As + (half * 64 + wv * 16) * 32;
            ushort_t* lB = Bs + (half * 64 + wv * 16) * 32;
            __builtin_amdgcn_global_load_lds(
                (const __attribute__((address_space(1))) unsigned int*)gA,
                (__attribute__((address_space(3))) unsigned int*)lA, 16, 0, 0);
            __builtin_amdgcn_global_load_lds(
                (const __attribute__((address_space(1))) unsigned int*)gB,
                (__attribute__((address_space(3))) unsigned int*)lB, 16, 0, 0);
        }
        __syncthreads();

        short8 af[4], bf[4];
#pragma unroll
        for (int mt = 0; mt < 4; ++mt)
            af[mt] = *(const short8*)&As[(wm * 64 + mt * 16 + lm) * 32 + quad * 8];
#pragma unroll
        for (int nt = 0; nt < 4; ++nt)
            bf[nt] = *(const short8*)&Bs[(wn * 64 + nt * 16 + lm) * 32 + quad * 8];
#pragma unroll
        for (int mt = 0; mt < 4; ++mt)
#pragma unroll
            for (int nt = 0; nt < 4; ++nt)
                acc[mt][nt] = __builtin_amdgcn_mfma_f32_16x16x32_bf16(
                    af[mt], bf[nt], acc[mt][nt], 0, 0, 0);
    }

    const bool isqk = colC < 2 * CC;   // q or k section
    if (isqk) {
#pragma unroll
        for (int mt = 0; mt < 4; ++mt)
#pragma unroll
            for (int r = 0; r < 4; ++r) {
                const int row = rowC + wm * 64 + mt * 16 + quad * 4 + r;
                ushort_t* Cp = C + (size_t)row * N + colC + wn * 64 + lm;
                const int t = row & (TT - 1);
                float ss = 0.f;
#pragma unroll
                for (int nt = 0; nt < 4; ++nt) ss += acc[mt][nt][r] * acc[mt][nt][r];
                ss += __shfl_xor(ss, 1);
                ss += __shfl_xor(ss, 2);
                ss += __shfl_xor(ss, 4);
                ss += __shfl_xor(ss, 8);
                const float rinv = rsqrtf(ss * (1.0f / 64.0f) + 1e-6f);
                const float c0 = cosb[t * 32 + lm];
                const float c1 = cosb[t * 32 + 16 + lm];
                const float s0 = sinb[t * 32 + lm];
                const float s1 = sinb[t * 32 + 16 + lm];
                const float o0 = acc[mt][0][r] * c0 + acc[mt][2][r] * s0;
                const float o1 = acc[mt][1][r] * c1 + acc[mt][3][r] * s1;
                const float o2 = acc[mt][2][r] * c0 - acc[mt][0][r] * s0;
                const float o3 = acc[mt][3][r] * c1 - acc[mt][1][r] * s1;
                Cp[0]  = f2bf(o0 * rinv);
                Cp[16] = f2bf(o1 * rinv);
                Cp[32] = f2bf(o2 * rinv);
                Cp[48] = f2bf(o3 * rinv);
            }
    } else {
        // v: write transposed. Lane's 4 r-values are 4 consecutive t at one
        // (h,d) row -> one packed 8B store each nt.
#pragma unroll
        for (int mt = 0; mt < 4; ++mt) {
            const int row0 = rowC + wm * 64 + mt * 16 + quad * 4;
            const int bb = row0 >> 11;         // batch
            const int tt = row0 & (TT - 1);    // t of r=0
#pragma unroll
            for (int nt = 0; nt < 4; ++nt) {
                const int hd = colC - 2 * CC + wn * 64 + nt * 16 + lm;
                short4_t pk;
                pk[0] = (short)f2bf(acc[mt][nt][0]);
                pk[1] = (short)f2bf(acc[mt][nt][1]);
                pk[2] = (short)f2bf(acc[mt][nt][2]);
                pk[3] = (short)f2bf(acc[mt][nt][3]);
                *(short4_t*)(vtb + (size_t)(bb * CC + hd) * TT + tt) = pk;
            }
        }
    }
}

// ---------------------------------------------------------------------------
// bf16 MFMA flash attention, fixed-max softmax, one q-tile per block.
// Swapped QK^T (A=K, B=Q): lane (quad,lm) holds P[k=16i+4quad+r][q=w*16+lm].
// k is relabeled (pi) so the lane's cvt_pk'd pairs directly form the PV
// A-fragment -- P never touches LDS. V staged into LDS at pi-permuted
// positions. Row sums via MFMA against a ones fragment (lands in the same
// C rows as O). Double-buffered staging: global loads for tile kt+1 issued
// before compute of kt; ds_write + single barrier at loop bottom.
// ---------------------------------------------------------------------------
__global__ __launch_bounds__(256, 3) void attn_mfma(ushort_t* __restrict__ qkv,
                                                    const ushort_t* __restrict__ vt) {
    const int qt = 31 - (int)blockIdx.x;   // longest blocks dispatched first
    const int h  = blockIdx.y;
    const int b  = blockIdx.z;
    const int tid  = threadIdx.x;
    const int w    = tid >> 6;
    const int lane = tid & 63;
    const int quad = lane >> 4;
    const int lm   = lane & 15;
    const int qloc = w * 16 + lm;          // q row within tile for this lane

    __shared__ ushort_t Ks[2][64][72];     // K[n][d]
    __shared__ ushort_t Vs[2][64][72];     // V^T[d][kappa], kappa = pi-permuted k

    // q fragments (B-operand: col=lm ~ q row, k-elems quad*8+j)
    short8 qf[2];
    {
        const ushort_t* qa = qkv + (size_t)(b * TT + qt * 64 + w * 16 + lm) * (3 * CC) + h * DD;
        qf[0] = *(const short8*)(qa + quad * 8);
        qf[1] = *(const short8*)(qa + 32 + quad * 8);
    }

    f32x4 O[4];
#pragma unroll
    for (int dt = 0; dt < 4; ++dt) O[dt] = (f32x4){0.f, 0.f, 0.f, 0.f};
    f32x4 lac = (f32x4){0.f, 0.f, 0.f, 0.f};

    const short one_bf = (short)0x3F80;    // bf16 1.0
    const short8 vones = {one_bf, one_bf, one_bf, one_bf, one_bf, one_bf, one_bf, one_bf};

    // staging indices
    const int sn = tid >> 2;               // K row (t) / V row (d)
    const int si = tid & 3;
    const int sd = si * 16;
    // kappa base for the V permutation: k_phys 16*si+4q+r -> kappa kb+8q+r
    const int kb = ((si >> 1) << 5) + ((si & 1) << 2);

    short8 k0v, k1v, v0v, v1v;
    auto stage_load = [&](int kt) {
        const ushort_t* kp = qkv + (size_t)(b * TT + kt * 64 + sn) * (3 * CC) + CC + h * DD + sd;
        k0v = *(const short8*)kp;
        k1v = *(const short8*)(kp + 8);
        const ushort_t* vp = vt + (size_t)(b * CC + h * DD + sn) * TT + kt * 64 + sd;
        v0v = *(const short8*)vp;
        v1v = *(const short8*)(vp + 8);
    };
    auto stage_write = [&](int bf) {
        *(short8*)&Ks[bf][sn][sd]     = k0v;
        *(short8*)&Ks[bf][sn][sd + 8] = k1v;
        *(short4_t*)&Vs[bf][sn][kb]      = __builtin_shufflevector(v0v, v0v, 0, 1, 2, 3);
        *(short4_t*)&Vs[bf][sn][kb + 8]  = __builtin_shufflevector(v0v, v0v, 4, 5, 6, 7);
        *(short4_t*)&Vs[bf][sn][kb + 16] = __builtin_shufflevector(v1v, v1v, 0, 1, 2, 3);
        *(short4_t*)&Vs[bf][sn][kb + 24] = __builtin_shufflevector(v1v, v1v, 4, 5, 6, 7);
    };

    // exp + pack: lane's own p values, cvt_pk'd, ARE its PV A-fragment
    auto softmax_pack = [&](const f32x4 (&sf)[4], short8 (&pa)[2], bool diag) {
        int dw[8];
#pragma unroll
        for (int i = 0; i < 4; ++i) {
            float pv[4];
#pragma unroll
            for (int r = 0; r < 4; ++r) {
                const float s = fmaf(sf[i][r], 0.125f, -8.0f);
                float p = __expf(s);   // scores provably in [-8,8] after rmsnorm
                if (diag) {
                    const int kloc = i * 16 + quad * 4 + r;
                    p = (kloc <= qloc) ? p : 0.0f;
                }
                pv[r] = p;
            }
            asm("v_cvt_pk_bf16_f32 %0, %1, %2" : "=v"(dw[i * 2 + 0]) : "v"(pv[0]), "v"(pv[1]));
            asm("v_cvt_pk_bf16_f32 %0, %1, %2" : "=v"(dw[i * 2 + 1]) : "v"(pv[2]), "v"(pv[3]));
        }
        int4v w0 = {dw[0], dw[1], dw[2], dw[3]};
        int4v w1 = {dw[4], dw[5], dw[6], dw[7]};
        pa[0] = __builtin_bit_cast(short8, w0);
        pa[1] = __builtin_bit_cast(short8, w1);
    };

    // prologue: stage tile 0
    stage_load(0);
    stage_write(0);
    __syncthreads();

    int cur = 0;
    for (int kt = 0; kt <= qt; ++kt) {
        if (kt < qt) stage_load(kt + 1);   // issue next-tile globals early

        // K fragments (A-operand: row=lm ~ K row, k-elems quad*8+j)
        short8 kf[2][4];
#pragma unroll
        for (int kk = 0; kk < 2; ++kk)
#pragma unroll
            for (int i = 0; i < 4; ++i)
                kf[kk][i] = *(const short8*)&Ks[cur][i * 16 + lm][kk * 32 + quad * 8];

        // S^T = K @ Q^T : sf[i][r] = S[k=16i+4quad+r][q=w*16+lm]
        f32x4 sf[4];
#pragma unroll
        for (int i = 0; i < 4; ++i) sf[i] = (f32x4){0.f, 0.f, 0.f, 0.f};
#pragma unroll
        for (int kk = 0; kk < 2; ++kk)
#pragma unroll
            for (int i = 0; i < 4; ++i)
                sf[i] = __builtin_amdgcn_mfma_f32_16x16x32_bf16(kf[kk][i], qf[kk],
                                                                sf[i], 0, 0, 0);

        short8 pa[2];
        if (kt == qt) softmax_pack(sf, pa, true);
        else          softmax_pack(sf, pa, false);

        // PV: O[q][d] += P[q][pi(kappa)] * V[pi(kappa)][d]; l via ones column
#pragma unroll
        for (int kk = 0; kk < 2; ++kk) {
#pragma unroll
            for (int dt = 0; dt < 4; ++dt) {
                const short8 vf = *(const short8*)&Vs[cur][dt * 16 + lm][kk * 32 + quad * 8];
                O[dt] = __builtin_amdgcn_mfma_f32_16x16x32_bf16(pa[kk], vf, O[dt], 0, 0, 0);
            }
            lac = __builtin_amdgcn_mfma_f32_16x16x32_bf16(pa[kk], vones, lac, 0, 0, 0);
        }

        if (kt < qt) stage_write(cur ^ 1);
        __syncthreads();
        cur ^= 1;
    }

    // epilogue: O row (quad*4+r) matches lac row; no cross-lane reduce needed
#pragma unroll
    for (int r = 0; r < 4; ++r) {
        const float inv_l = 1.0f / lac[r];
        ushort_t* yp = qkv + (size_t)(b * TT + qt * 64 + w * 16 + quad * 4 + r) * (3 * CC)
                           + 2 * CC + h * DD + lm;
#pragma unroll
        for (int dt = 0; dt < 4; ++dt) yp[dt * 16] = f2bf(O[dt][r] * inv_l);
    }
}

// ---------------------------------------------------------------------------
extern "C" void kernel_launch(void* const* d_in, const int* in_sizes, int n_in,
                              void* d_out, int out_size, void* d_ws, size_t ws_size,
                              hipStream_t stream) {
    const float* x      = (const float*)d_in[0];   // (4,2048,1024)
    const float* cosb   = (const float*)d_in[1];   // (1,2048,1,32)
    const float* sinb   = (const float*)d_in[2];
    const float* w_attn = (const float*)d_in[3];   // (3072,1024)
    const float* w_proj = (const float*)d_in[4];   // (1024,1024)
    float* out = (float*)d_out;                    // (4,2048,1024)

    // workspace layout (bf16 elements)
    ushort_t* qkvb = (ushort_t*)d_ws;                       // 8192*3072 (q,k; v-cols hold y)
    ushort_t* vtb  = qkvb + (size_t)8192 * 3072;            // 4096*2048 = 8192*1024 (V^T)
    ushort_t* xb   = vtb  + (size_t)8192 * 1024;            // 8192*1024
    ushort_t* wab  = xb   + (size_t)8192 * 1024;            // 3072*1024
    ushort_t* wpb  = wab  + (size_t)3072 * 1024;            // 1024*1024

    cast_bf16<<<(8192 * 1024 / 8 + 255) / 256, 256, 0, stream>>>(x, xb, 8192 * 1024 / 8);
    cast_bf16<<<(3072 * 1024 / 8 + 255) / 256, 256, 0, stream>>>(w_attn, wab, 3072 * 1024 / 8);
    cast_bf16<<<(1024 * 1024 / 8 + 255) / 256, 256, 0, stream>>>(w_proj, wpb, 1024 * 1024 / 8);

    // qkv = x @ w_attn^T; rope+rmsnorm on q,k; v transposed into vtb
    gemm_qkv<<<dim3(3072 / 128, 8192 / 128), 256, 0, stream>>>(
        xb, wab, qkvb, vtb, cosb, sinb, 8192, 3072, 1024);

    // causal attention -> y into qkvb's v-columns (one q-tile per block)
    attn_mfma<<<dim3(32, HH, 4), 256, 0, stream>>>(qkvb, vtb);

    // out = y @ w_proj^T (fp32 out), A = qkvb v-columns with lda=3072
    gemm_bt<true><<<dim3(1024 / 128, 8192 / 128), 256, 0, stream>>>(
        qkvb + 2 * CC, wpb, out, 8192, 1024, 1024, 3 * CC);
}

// Round 5
// 302.902 us; speedup vs baseline: 1.4462x; 1.0310x over previous
//
#include <hip/hip_runtime.h>
#include <hip/hip_bf16.h>
#include <math.h>

// Problem: B=4, T=2048, C=1024, H=16, D=64, d_half=32
// Dataflow:
//   cast x, w_attn, w_proj -> bf16
//   qkvb = xb @ wab^T  rope+rmsnorm fused into q/k epilogue; v written
//          PRE-TRANSPOSED to vt[b*C + h*64 + d][t] (packed short4 over r)
//   attn (bf16 MFMA flash, fixed-max softmax):
//          QBLK=256 per block (each wave owns 64 q-rows = 4 subtiles) so
//          each staged 64-key tile is amortized over 4x compute; swapped
//          QK^T (mfma(K,Q)) with k-relabeling keeps P in registers (packed
//          p values ARE the PV A-fragment); kf/vf register-resident,
//          reused across subtiles; row sums via ones-column MFMA;
//          double-buffered LDS staging, one barrier per tile.
//          NOTE: no s_setprio, no inline asm (isolating round-4 failure).
//          y written into qkvb's dead v-columns.
//   out  = (qkvb v-cols as y, lda=3072) @ wpb^T  (fp32 out)

#define TT 2048
#define CC 1024
#define HH 16
#define DD 64

typedef __attribute__((ext_vector_type(8))) short short8;
typedef __attribute__((ext_vector_type(4))) short short4_t;
typedef __attribute__((ext_vector_type(4))) float f32x4;
typedef unsigned short ushort_t;

// fp32 -> bf16 (RNE, finite inputs only)
__device__ __forceinline__ ushort_t f2bf(float f) {
    unsigned u = __builtin_bit_cast(unsigned, f);
    u = (u + 0x7fffu + ((u >> 16) & 1u)) >> 16;
    return (ushort_t)u;
}

// ---------------------------------------------------------------------------
// float -> bf16 cast, 8 elements/thread
// ---------------------------------------------------------------------------
__global__ __launch_bounds__(256) void cast_bf16(const float* __restrict__ in,
                                                 ushort_t* __restrict__ out, int n8) {
    const int i = blockIdx.x * 256 + threadIdx.x;
    if (i >= n8) return;
    const float4* p = (const float4*)in + (size_t)i * 2;
    float4 f0 = p[0], f1 = p[1];
    short8 v;
    v[0] = (short)f2bf(f0.x); v[1] = (short)f2bf(f0.y);
    v[2] = (short)f2bf(f0.z); v[3] = (short)f2bf(f0.w);
    v[4] = (short)f2bf(f1.x); v[5] = (short)f2bf(f1.y);
    v[6] = (short)f2bf(f1.z); v[7] = (short)f2bf(f1.w);
    *(short8*)(out + (size_t)i * 8) = v;
}

// ---------------------------------------------------------------------------
// bf16 MFMA GEMM (m97 structure): C = A[M,K](lda) * B[N,K]^T, 128x128 tile.
// ---------------------------------------------------------------------------
template <bool OUTF32>
__global__ __launch_bounds__(256) void gemm_bt(const ushort_t* __restrict__ A,
                                               const ushort_t* __restrict__ B,
                                               void* __restrict__ C,
                                               int M, int N, int K, int lda) {
    __shared__ ushort_t As[128 * 32];
    __shared__ ushort_t Bs[128 * 32];

    const int tid  = threadIdx.x;
    const int wv   = tid >> 6;
    const int ln   = tid & 63;
    const int quad = ln >> 4;
    const int lm   = ln & 15;
    const int wm   = wv & 1;
    const int wn   = wv >> 1;
    const int rowC = blockIdx.y * 128;
    const int colC = blockIdx.x * 128;

    const int srow = wv * 16 + (ln >> 2);
    const int skq  = (ln & 3) * 8;

    f32x4 acc[4][4];
#pragma unroll
    for (int i = 0; i < 4; ++i)
#pragma unroll
        for (int j = 0; j < 4; ++j) acc[i][j] = (f32x4){0.f, 0.f, 0.f, 0.f};

    for (int k0 = 0; k0 < K; k0 += 32) {
        __syncthreads();
#pragma unroll
        for (int half = 0; half < 2; ++half) {
            const ushort_t* gA = A + (size_t)(rowC + half * 64 + srow) * lda + k0 + skq;
            const ushort_t* gB = B + (size_t)(colC + half * 64 + srow) * K + k0 + skq;
            ushort_t* lA = As + (half * 64 + wv * 16) * 32;
            ushort_t* lB = Bs + (half * 64 + wv * 16) * 32;
            __builtin_amdgcn_global_load_lds(
                (const __attribute__((address_space(1))) unsigned int*)gA,
                (__attribute__((address_space(3))) unsigned int*)lA, 16, 0, 0);
            __builtin_amdgcn_global_load_lds(
                (const __attribute__((address_space(1))) unsigned int*)gB,
                (__attribute__((address_space(3))) unsigned int*)lB, 16, 0, 0);
        }
        __syncthreads();

        short8 af[4], bf[4];
#pragma unroll
        for (int mt = 0; mt < 4; ++mt)
            af[mt] = *(const short8*)&As[(wm * 64 + mt * 16 + lm) * 32 + quad * 8];
#pragma unroll
        for (int nt = 0; nt < 4; ++nt)
            bf[nt] = *(const short8*)&Bs[(wn * 64 + nt * 16 + lm) * 32 + quad * 8];
#pragma unroll
        for (int mt = 0; mt < 4; ++mt)
#pragma unroll
            for (int nt = 0; nt < 4; ++nt)
                acc[mt][nt] = __builtin_amdgcn_mfma_f32_16x16x32_bf16(
                    af[mt], bf[nt], acc[mt][nt], 0, 0, 0);
    }

#pragma unroll
    for (int mt = 0; mt < 4; ++mt)
#pragma unroll
        for (int r = 0; r < 4; ++r) {
            const size_t row = rowC + wm * 64 + mt * 16 + quad * 4 + r;
#pragma unroll
            for (int nt = 0; nt < 4; ++nt) {
                const size_t col = colC + wn * 64 + nt * 16 + lm;
                if (OUTF32) ((float*)C)[row * N + col] = acc[mt][nt][r];
                else        ((ushort_t*)C)[row * N + col] = f2bf(acc[mt][nt][r]);
            }
        }
}

// ---------------------------------------------------------------------------
// GEMM1 with fused rope+rmsnorm epilogue on q/k. v-section written
// TRANSPOSED to vtb[(b*CC + h*64 + d)][t] as packed short4 (r = 4 consec t).
// ---------------------------------------------------------------------------
__global__ __launch_bounds__(256) void gemm_qkv(const ushort_t* __restrict__ A,
                                                const ushort_t* __restrict__ B,
                                                ushort_t* __restrict__ C,
                                                ushort_t* __restrict__ vtb,
                                                const float* __restrict__ cosb,
                                                const float* __restrict__ sinb,
                                                int M, int N, int K) {
    __shared__ ushort_t As[128 * 32];
    __shared__ ushort_t Bs[128 * 32];

    const int tid  = threadIdx.x;
    const int wv   = tid >> 6;
    const int ln   = tid & 63;
    const int quad = ln >> 4;
    const int lm   = ln & 15;
    const int wm   = wv & 1;
    const int wn   = wv >> 1;
    const int rowC = blockIdx.y * 128;
    const int colC = blockIdx.x * 128;

    const int srow = wv * 16 + (ln >> 2);
    const int skq  = (ln & 3) * 8;

    f32x4 acc[4][4];
#pragma unroll
    for (int i = 0; i < 4; ++i)
#pragma unroll
        for (int j = 0; j < 4; ++j) acc[i][j] = (f32x4){0.f, 0.f, 0.f, 0.f};

    for (int k0 = 0; k0 < K; k0 += 32) {
        __syncthreads();
#pragma unroll
        for (int half = 0; half < 2; ++half) {
            const ushort_t* gA = A + (size_t)(rowC + half * 64 + srow) * K + k0 + skq;
            const ushort_t* gB = B + (size_t)(colC + half * 64 + srow) * K + k0 + skq;
            ushort_t* lA = As + (half * 64 + wv * 16) * 32;
            ushort_t* lB = Bs + (half * 64 + wv * 16) * 32;
            __builtin_amdgcn_global_load_lds(
                (const __attribute__((address_space(1))) unsigned int*)gA,
                (__attribute__((address_space(3))) unsigned int*)lA, 16, 0, 0);
            __builtin_amdgcn_global_load_lds(
                (const __attribute__((address_space(1))) unsigned int*)gB,
                (__attribute__((address_space(3))) unsigned int*)lB, 16, 0, 0);
        }
        __syncthreads();

        short8 af[4], bf[4];
#pragma unroll
        for (int mt = 0; mt < 4; ++mt)
            af[mt] = *(const short8*)&As[(wm * 64 + mt * 16 + lm) * 32 + quad * 8];
#pragma unroll
        for (int nt = 0; nt < 4; ++nt)
            bf[nt] = *(const short8*)&Bs[(wn * 64 + nt * 16 + lm) * 32 + quad * 8];
#pragma unroll
        for (int mt = 0; mt < 4; ++mt)
#pragma unroll
            for (int nt = 0; nt < 4; ++nt)
                acc[mt][nt] = __builtin_amdgcn_mfma_f32_16x16x32_bf16(
                    af[mt], bf[nt], acc[mt][nt], 0, 0, 0);
    }

    const bool isqk = colC < 2 * CC;   // q or k section
    if (isqk) {
#pragma unroll
        for (int mt = 0; mt < 4; ++mt)
#pragma unroll
            for (int r = 0; r < 4; ++r) {
                const int row = rowC + wm * 64 + mt * 16 + quad * 4 + r;
                ushort_t* Cp = C + (size_t)row * N + colC + wn * 64 + lm;
                const int t = row & (TT - 1);
                float ss = 0.f;
#pragma unroll
                for (int nt = 0; nt < 4; ++nt) ss += acc[mt][nt][r] * acc[mt][nt][r];
                ss += __shfl_xor(ss, 1);
                ss += __shfl_xor(ss, 2);
                ss += __shfl_xor(ss, 4);
                ss += __shfl_xor(ss, 8);
                const float rinv = rsqrtf(ss * (1.0f / 64.0f) + 1e-6f);
                const float c0 = cosb[t * 32 + lm];
                const float c1 = cosb[t * 32 + 16 + lm];
                const float s0 = sinb[t * 32 + lm];
                const float s1 = sinb[t * 32 + 16 + lm];
                const float o0 = acc[mt][0][r] * c0 + acc[mt][2][r] * s0;
                const float o1 = acc[mt][1][r] * c1 + acc[mt][3][r] * s1;
                const float o2 = acc[mt][2][r] * c0 - acc[mt][0][r] * s0;
                const float o3 = acc[mt][3][r] * c1 - acc[mt][1][r] * s1;
                Cp[0]  = f2bf(o0 * rinv);
                Cp[16] = f2bf(o1 * rinv);
                Cp[32] = f2bf(o2 * rinv);
                Cp[48] = f2bf(o3 * rinv);
            }
    } else {
        // v: write transposed. Lane's 4 r-values are 4 consecutive t at one
        // (h,d) row -> one packed 8B store each nt.
#pragma unroll
        for (int mt = 0; mt < 4; ++mt) {
            const int row0 = rowC + wm * 64 + mt * 16 + quad * 4;
            const int bb = row0 >> 11;         // batch
            const int tt = row0 & (TT - 1);    // t of r=0
#pragma unroll
            for (int nt = 0; nt < 4; ++nt) {
                const int hd = colC - 2 * CC + wn * 64 + nt * 16 + lm;
                short4_t pk;
                pk[0] = (short)f2bf(acc[mt][nt][0]);
                pk[1] = (short)f2bf(acc[mt][nt][1]);
                pk[2] = (short)f2bf(acc[mt][nt][2]);
                pk[3] = (short)f2bf(acc[mt][nt][3]);
                *(short4_t*)(vtb + (size_t)(bb * CC + hd) * TT + tt) = pk;
            }
        }
    }
}

// ---------------------------------------------------------------------------
// bf16 MFMA flash attention, fixed-max softmax, QBLK=256 per block.
// Each wave owns 64 q-rows (4 subtiles). Swapped QK^T (A=K, B=Q): lane
// (quad,lm) holds P[k=16i+quad*4+r][q = subtile col lm]. k relabeled (pi)
// so the lane's packed p values form the PV A-fragment directly; V staged
// at pi-permuted positions. kf/vf registers reused across all 4 subtiles.
// Row sums via ones-column MFMA. Double-buffered staging, one barrier/tile.
// Wave w's diag tile is kt==qb*4+w; beyond it the wave stages+barriers only.
// No s_setprio / inline asm this round (round-4 failure isolation).
// ---------------------------------------------------------------------------
__global__ __launch_bounds__(256, 2) void attn_mfma(ushort_t* __restrict__ qkv,
                                                    const ushort_t* __restrict__ vt) {
    const int qb = 7 - (int)blockIdx.x;    // 0..7, longest blocks first
    const int h  = blockIdx.y;
    const int b  = blockIdx.z;
    const int tid  = threadIdx.x;
    const int w    = tid >> 6;
    const int lane = tid & 63;
    const int quad = lane >> 4;
    const int lm   = lane & 15;

    __shared__ ushort_t Ks[2][64][72];     // K[n][d]
    __shared__ ushort_t Vs[2][64][72];     // V^T[d][kappa], kappa = pi-permuted k

    // q fragments: wave w owns q rows qb*256 + w*64 + qs*16 + lm
    short8 qf[4][2];
#pragma unroll
    for (int qs = 0; qs < 4; ++qs) {
        const ushort_t* qa = qkv + (size_t)(b * TT + qb * 256 + w * 64 + qs * 16 + lm) * (3 * CC) + h * DD;
        qf[qs][0] = *(const short8*)(qa + quad * 8);
        qf[qs][1] = *(const short8*)(qa + 32 + quad * 8);
    }

    f32x4 O[4][4];
    f32x4 lac[4];
#pragma unroll
    for (int qs = 0; qs < 4; ++qs) {
        lac[qs] = (f32x4){0.f, 0.f, 0.f, 0.f};
#pragma unroll
        for (int dt = 0; dt < 4; ++dt) O[qs][dt] = (f32x4){0.f, 0.f, 0.f, 0.f};
    }

    const short one_bf = (short)0x3F80;    // bf16 1.0
    const short8 vones = {one_bf, one_bf, one_bf, one_bf, one_bf, one_bf, one_bf, one_bf};

    // staging indices
    const int sn = tid >> 2;               // K row (t) / V row (d)
    const int si = tid & 3;
    const int sd = si * 16;
    // kappa base for the V permutation: k_phys 16*si+4q+r -> kappa kb+8q+r
    const int kb = ((si >> 1) << 5) + ((si & 1) << 2);

    short8 k0v, k1v, v0v, v1v;
    auto stage_load = [&](int kt) {
        const ushort_t* kp = qkv + (size_t)(b * TT + kt * 64 + sn) * (3 * CC) + CC + h * DD + sd;
        k0v = *(const short8*)kp;
        k1v = *(const short8*)(kp + 8);
        const ushort_t* vp = vt + (size_t)(b * CC + h * DD + sn) * TT + kt * 64 + sd;
        v0v = *(const short8*)vp;
        v1v = *(const short8*)(vp + 8);
    };
    auto stage_write = [&](int bufi) {
        *(short8*)&Ks[bufi][sn][sd]     = k0v;
        *(short8*)&Ks[bufi][sn][sd + 8] = k1v;
        *(short4_t*)&Vs[bufi][sn][kb]      = __builtin_shufflevector(v0v, v0v, 0, 1, 2, 3);
        *(short4_t*)&Vs[bufi][sn][kb + 8]  = __builtin_shufflevector(v0v, v0v, 4, 5, 6, 7);
        *(short4_t*)&Vs[bufi][sn][kb + 16] = __builtin_shufflevector(v1v, v1v, 0, 1, 2, 3);
        *(short4_t*)&Vs[bufi][sn][kb + 24] = __builtin_shufflevector(v1v, v1v, 4, 5, 6, 7);
    };

    const int ktmax = qb * 4 + 3;          // block's last kv tile
    const int ktw   = qb * 4 + w;          // this wave's diagonal tile

    // prologue: stage tile 0
    stage_load(0);
    stage_write(0);
    __syncthreads();

    int cur = 0;
    for (int kt = 0; kt <= ktmax; ++kt) {
        if (kt < ktmax) stage_load(kt + 1);    // issue next-tile globals early

        if (kt <= ktw) {
            // K / V fragments: register-resident, reused by all 4 subtiles
            short8 kf[2][4], vf[2][4];
#pragma unroll
            for (int kk = 0; kk < 2; ++kk)
#pragma unroll
                for (int i = 0; i < 4; ++i) {
                    kf[kk][i] = *(const short8*)&Ks[cur][i * 16 + lm][kk * 32 + quad * 8];
                    vf[kk][i] = *(const short8*)&Vs[cur][i * 16 + lm][kk * 32 + quad * 8];
                }
            const bool diag = (kt == ktw);

#pragma unroll
            for (int qs = 0; qs < 4; ++qs) {
                // S^T = K @ Q^T : sf[i][r] = S[k=16i+quad*4+r][q=qs*16+lm]
                f32x4 sf[4];
#pragma unroll
                for (int i = 0; i < 4; ++i) sf[i] = (f32x4){0.f, 0.f, 0.f, 0.f};
#pragma unroll
                for (int kk = 0; kk < 2; ++kk)
#pragma unroll
                    for (int i = 0; i < 4; ++i)
                        sf[i] = __builtin_amdgcn_mfma_f32_16x16x32_bf16(
                            kf[kk][i], qf[qs][kk], sf[i], 0, 0, 0);

                // exp + pack (plain f2bf): lane's own p values ARE its PV
                // A-fragment under the pi relabeling: pa[kk][(i&1)*4+r]
                short8 pa0 = {0, 0, 0, 0, 0, 0, 0, 0};
                short8 pa1 = {0, 0, 0, 0, 0, 0, 0, 0};
#pragma unroll
                for (int i = 0; i < 4; ++i)
#pragma unroll
                    for (int r = 0; r < 4; ++r) {
                        const float s = fmaf(sf[i][r], 0.125f, -8.0f);
                        float p = __expf(s);   // scores in [-8,8] after rmsnorm
                        if (diag) {
                            const int kloc = i * 16 + quad * 4 + r;
                            p = (kloc <= qs * 16 + lm) ? p : 0.0f;
                        }
                        const short pb = (short)f2bf(p);
                        if (i < 2) pa0[(i & 1) * 4 + r] = pb;
                        else       pa1[(i & 1) * 4 + r] = pb;
                    }

                // PV: O[q][d] += P[q][pi(kappa)] * V[pi(kappa)][d]; l via ones
#pragma unroll
                for (int dt = 0; dt < 4; ++dt)
                    O[qs][dt] = __builtin_amdgcn_mfma_f32_16x16x32_bf16(
                        pa0, vf[0][dt], O[qs][dt], 0, 0, 0);
                lac[qs] = __builtin_amdgcn_mfma_f32_16x16x32_bf16(
                    pa0, vones, lac[qs], 0, 0, 0);
#pragma unroll
                for (int dt = 0; dt < 4; ++dt)
                    O[qs][dt] = __builtin_amdgcn_mfma_f32_16x16x32_bf16(
                        pa1, vf[1][dt], O[qs][dt], 0, 0, 0);
                lac[qs] = __builtin_amdgcn_mfma_f32_16x16x32_bf16(
                    pa1, vones, lac[qs], 0, 0, 0);
            }
        }

        if (kt < ktmax) stage_write(cur ^ 1);
        __syncthreads();
        cur ^= 1;
    }

    // epilogue: O row (quad*4+r) matches lac row; no cross-lane reduce needed
#pragma unroll
    for (int qs = 0; qs < 4; ++qs)
#pragma unroll
        for (int r = 0; r < 4; ++r) {
            const float inv_l = 1.0f / lac[qs][r];
            ushort_t* yp = qkv + (size_t)(b * TT + qb * 256 + w * 64 + qs * 16 + quad * 4 + r) * (3 * CC)
                               + 2 * CC + h * DD + lm;
#pragma unroll
            for (int dt = 0; dt < 4; ++dt) yp[dt * 16] = f2bf(O[qs][dt][r] * inv_l);
        }
}

// ---------------------------------------------------------------------------
extern "C" void kernel_launch(void* const* d_in, const int* in_sizes, int n_in,
                              void* d_out, int out_size, void* d_ws, size_t ws_size,
                              hipStream_t stream) {
    const float* x      = (const float*)d_in[0];   // (4,2048,1024)
    const float* cosb   = (const float*)d_in[1];   // (1,2048,1,32)
    const float* sinb   = (const float*)d_in[2];
    const float* w_attn = (const float*)d_in[3];   // (3072,1024)
    const float* w_proj = (const float*)d_in[4];   // (1024,1024)
    float* out = (float*)d_out;                    // (4,2048,1024)

    // workspace layout (bf16 elements)
    ushort_t* qkvb = (ushort_t*)d_ws;                       // 8192*3072 (q,k; v-cols hold y)
    ushort_t* vtb  = qkvb + (size_t)8192 * 3072;            // 4096*2048 = 8192*1024 (V^T)
    ushort_t* xb   = vtb  + (size_t)8192 * 1024;            // 8192*1024
    ushort_t* wab  = xb   + (size_t)8192 * 1024;            // 3072*1024
    ushort_t* wpb  = wab  + (size_t)3072 * 1024;            // 1024*1024

    cast_bf16<<<(8192 * 1024 / 8 + 255) / 256, 256, 0, stream>>>(x, xb, 8192 * 1024 / 8);
    cast_bf16<<<(3072 * 1024 / 8 + 255) / 256, 256, 0, stream>>>(w_attn, wab, 3072 * 1024 / 8);
    cast_bf16<<<(1024 * 1024 / 8 + 255) / 256, 256, 0, stream>>>(w_proj, wpb, 1024 * 1024 / 8);

    // qkv = x @ w_attn^T; rope+rmsnorm on q,k; v transposed into vtb
    gemm_qkv<<<dim3(3072 / 128, 8192 / 128), 256, 0, stream>>>(
        xb, wab, qkvb, vtb, cosb, sinb, 8192, 3072, 1024);

    // causal attention -> y into qkvb's v-columns (QBLK=256 per block)
    attn_mfma<<<dim3(8, HH, 4), 256, 0, stream>>>(qkvb, vtb);

    // out = y @ w_proj^T (fp32 out), A = qkvb v-columns with lda=3072
    gemm_bt<true><<<dim3(1024 / 128, 8192 / 128), 256, 0, stream>>>(
        qkvb + 2 * CC, wpb, out, 8192, 1024, 1024, 3 * CC);
}